// Round 5
// baseline (610.647 us; speedup 1.0000x reference)
//
#include <hip/hip_runtime.h>
#include <hip/hip_bf16.h>

// GetAffs: seg [1,1,4096,4096] f32 (integer labels), out [8,4096,4096] f32.
// out[o][i][j] = (zeroext(seg)[i+ox][j+oy] == seg[i][j]) ? 1.0f : 0.0f
// OFFSETS: (-1,0),(0,-1),(-2,0),(0,-2),(-4,0),(0,-4),(-8,0),(0,-8)
//
// R4: ONE PLANE PER BLOCK (grid.z = 8). Each wave owns a single write stream
// (like the 6.3 TB/s copy kernel) instead of round-robining 8 streams 64 MB
// apart. Dispatch order writes plane 0 fully, then plane 1, ... -> sequential
// aggregate write traffic. seg is re-read per plane but is L3-resident (64 MB
// < 256 MB). NT stores (tested better in R2 vs R3).

#define IMG_H 4096
#define IMG_W 4096
#define BAND  16

typedef float floatx4 __attribute__((ext_vector_type(4)));

__device__ __forceinline__ float4 ld4(const float* p) { return *(const float4*)p; }

__device__ __forceinline__ void st4_nt(float* p, float4 v) {
    floatx4 x = { v.x, v.y, v.z, v.w };
    __builtin_nontemporal_store(x, (floatx4*)p);
}

__device__ __forceinline__ float4 eq4(float4 a, float4 b) {
    return make_float4(a.x == b.x ? 1.0f : 0.0f,
                       a.y == b.y ? 1.0f : 0.0f,
                       a.z == b.z ? 1.0f : 0.0f,
                       a.w == b.w ? 1.0f : 0.0f);
}

// One offset (OX,OY), BAND rows, 4 cols per thread.
template <int OX, int OY>
__device__ __forceinline__ void do_plane(const float* __restrict__ seg,
                                         float* __restrict__ po,
                                         int i0, int j) {
    const float4 zero4 = make_float4(0.f, 0.f, 0.f, 0.f);
#pragma unroll
    for (int u = 0; u < BAND; ++u) {
        const int i = i0 + u;
        const float* row = seg + (size_t)i * IMG_W;
        const float4 c = ld4(row + j);
        float4 nb;
        if (OY == 0) {
            // vertical: neighbor row i+OX (OX in {-1,-2,-4,-8}), zero if OOB
            nb = (i + OX >= 0) ? ld4(seg + (size_t)(i + OX) * IMG_W + j) : zero4;
        } else if (OY == -1) {
            const float4 l1 = (j >= 4) ? ld4(row + j - 4) : zero4;
            nb = make_float4(l1.w, c.x, c.y, c.z);
        } else if (OY == -2) {
            const float4 l1 = (j >= 4) ? ld4(row + j - 4) : zero4;
            nb = make_float4(l1.z, l1.w, c.x, c.y);
        } else if (OY == -4) {
            nb = (j >= 4) ? ld4(row + j - 4) : zero4;
        } else {  // OY == -8
            nb = (j >= 8) ? ld4(row + j - 8) : zero4;
        }
        st4_nt(po + (size_t)i * IMG_W + j, eq4(nb, c));
    }
}

__global__ __launch_bounds__(256) void GetAffs_83416854823610_kernel(
        const float* __restrict__ seg, float* __restrict__ out) {
    const int j  = (blockIdx.x * 256 + threadIdx.x) << 2;  // first of 4 cols
    const int i0 = blockIdx.y * BAND;                      // first row of band
    const size_t HW = (size_t)IMG_H * IMG_W;
    float* po = out + (size_t)blockIdx.z * HW;

    switch (blockIdx.z) {
        case 0: do_plane<-1,  0>(seg, po, i0, j); break;
        case 1: do_plane< 0, -1>(seg, po, i0, j); break;
        case 2: do_plane<-2,  0>(seg, po, i0, j); break;
        case 3: do_plane< 0, -2>(seg, po, i0, j); break;
        case 4: do_plane<-4,  0>(seg, po, i0, j); break;
        case 5: do_plane< 0, -4>(seg, po, i0, j); break;
        case 6: do_plane<-8,  0>(seg, po, i0, j); break;
        case 7: do_plane< 0, -8>(seg, po, i0, j); break;
    }
}

extern "C" void kernel_launch(void* const* d_in, const int* in_sizes, int n_in,
                              void* d_out, int out_size, void* d_ws, size_t ws_size,
                              hipStream_t stream) {
    const float* seg = (const float*)d_in[0];
    float* out = (float*)d_out;
    // x: 1024 col-groups / 256 threads = 4; y: 4096/16 = 256 bands; z: plane.
    dim3 grid((IMG_W / 4) / 256, IMG_H / BAND, 8);
    dim3 block(256);
    GetAffs_83416854823610_kernel<<<grid, block, 0, stream>>>(seg, out);
}